// Round 1
// baseline (278.905 us; speedup 1.0000x reference)
//
#include <hip/hip_runtime.h>
#include <hip/hip_bf16.h>

#define N 2048
#define B 16

// Kernel 1: Asum[b,i] = sum_k |s[b,i] - s[b,k]|
// grid = (N/256, B), block = 256. Row staged in LDS; inner loop reads are
// wave-uniform (broadcast, no bank conflicts).
__global__ __launch_bounds__(256) void asum_kernel(const float* __restrict__ s,
                                                   float* __restrict__ asum) {
    const int b = blockIdx.y;
    const int i = blockIdx.x * 256 + threadIdx.x;

    __shared__ float row[N];
    for (int k = threadIdx.x; k < N; k += 256)
        row[k] = s[b * N + k];
    __syncthreads();

    const float si = row[i];
    float acc = 0.0f;
#pragma unroll 8
    for (int k = 0; k < N; ++k)
        acc += fabsf(si - row[k]);

    asum[b * N + i] = acc;
}

// Kernel 2: one block per (b, j) output row.
// out[b,j,i] = softmax_i( s[b,i]*(2047-2j) - Asum[b,i] )
// Each thread owns 8 elements as two float4 chunks -> fully coalesced
// 16B/lane loads and stores.
__global__ __launch_bounds__(256) void softmax_rows(const float* __restrict__ s,
                                                    const float* __restrict__ asum,
                                                    float* __restrict__ out) {
    const int j = blockIdx.x;
    const int b = blockIdx.y;
    const int t = threadIdx.x;
    const int lane = t & 63;
    const int wave = t >> 6;

    const float cj = (float)(N - 1 - 2 * j);  // scaling[j] = n+1-2(j+1)

    const float4* s4 = (const float4*)(s + (size_t)b * N);
    const float4* a4 = (const float4*)(asum + (size_t)b * N);

    float4 sv0 = s4[t];
    float4 sv1 = s4[t + 256];
    float4 av0 = a4[t];
    float4 av1 = a4[t + 256];

    float v[8];
    v[0] = sv0.x * cj - av0.x;
    v[1] = sv0.y * cj - av0.y;
    v[2] = sv0.z * cj - av0.z;
    v[3] = sv0.w * cj - av0.w;
    v[4] = sv1.x * cj - av1.x;
    v[5] = sv1.y * cj - av1.y;
    v[6] = sv1.z * cj - av1.z;
    v[7] = sv1.w * cj - av1.w;

    // --- max reduction ---
    float m = v[0];
#pragma unroll
    for (int i = 1; i < 8; ++i) m = fmaxf(m, v[i]);
#pragma unroll
    for (int off = 32; off >= 1; off >>= 1)
        m = fmaxf(m, __shfl_xor(m, off));

    __shared__ float redm[4];
    __shared__ float reds[4];
    if (lane == 0) redm[wave] = m;
    __syncthreads();
    m = fmaxf(fmaxf(redm[0], redm[1]), fmaxf(redm[2], redm[3]));

    // --- exp + sum reduction (TAU = 1) ---
    float e[8];
    float sum = 0.0f;
#pragma unroll
    for (int i = 0; i < 8; ++i) {
        e[i] = __expf(v[i] - m);
        sum += e[i];
    }
#pragma unroll
    for (int off = 32; off >= 1; off >>= 1)
        sum += __shfl_xor(sum, off);
    if (lane == 0) reds[wave] = sum;
    __syncthreads();
    sum = (reds[0] + reds[1]) + (reds[2] + reds[3]);

    const float r = 1.0f / sum;

    float4 o0, o1;
    o0.x = e[0] * r; o0.y = e[1] * r; o0.z = e[2] * r; o0.w = e[3] * r;
    o1.x = e[4] * r; o1.y = e[5] * r; o1.z = e[6] * r; o1.w = e[7] * r;

    float4* o4 = (float4*)(out + ((size_t)b * N + j) * N);
    o4[t]       = o0;
    o4[t + 256] = o1;
}

extern "C" void kernel_launch(void* const* d_in, const int* in_sizes, int n_in,
                              void* d_out, int out_size, void* d_ws, size_t ws_size,
                              hipStream_t stream) {
    const float* scores = (const float*)d_in[0];
    float* out = (float*)d_out;
    float* asum = (float*)d_ws;  // needs B*N*4 = 128 KB

    dim3 g1(N / 256, B);
    asum_kernel<<<g1, 256, 0, stream>>>(scores, asum);

    dim3 g2(N, B);
    softmax_rows<<<g2, 256, 0, stream>>>(scores, asum, out);
}